// Round 1
// 345.234 us; speedup vs baseline: 1.0773x; 1.0773x over previous
//
#include <hip/hip_runtime.h>
#include <cstddef>

#define N_SAMPLES 16384
#define F_ 39
#define V_ 100000
#define E_ 16
#define H1_ 400
#define H2_ 400
#define FE_ (F_ * E_)  // 624

#define CS_BLOCKS 256
#define CS_CHUNK (N_SAMPLES / CS_BLOCKS)  // 64 rows per block
#define SPB 8                              // samples per block in fused_main

// ---- block-wide sum over 256 threads; result valid on threadIdx.x==0 ----
__device__ __forceinline__ float blockReduceSum256(float v, float* red) {
  int t = threadIdx.x;
  v += __shfl_xor(v, 32);
  v += __shfl_xor(v, 16);
  v += __shfl_xor(v, 8);
  v += __shfl_xor(v, 4);
  v += __shfl_xor(v, 2);
  v += __shfl_xor(v, 1);
  if ((t & 63) == 0) red[t >> 6] = v;
  __syncthreads();
  if (t == 0) v = red[0] + red[1] + red[2] + red[3];
  return v;
}

// ---- pre1:
//   blocks 0..255   : coalesced partial column-sums of Xv -> partial[b][f]
//   blocks 256..655 : w2red[k] = W2[k,:]·g2  (float4), w2g[k] = g1[k]*w2red[k]
__global__ __launch_bounds__(256) void pre1_kernel(
    const float* __restrict__ Xv, const float* __restrict__ W2,
    const float* __restrict__ g1, const float* __restrict__ g2,
    float* __restrict__ partial, float* __restrict__ w2red,
    float* __restrict__ w2g) {
  int b = blockIdx.x, t = threadIdx.x;
  if (b < CS_BLOCKS) {
    __shared__ float bins[F_];
    if (t < F_) bins[t] = 0.f;
    __syncthreads();
    const float* src = Xv + (size_t)b * CS_CHUNK * F_;
    // 64*39 = 2496 contiguous floats, fully coalesced
    for (int i = t; i < CS_CHUNK * F_; i += 256) {
      int f = i % F_;  // magic-mul, cheap
      atomicAdd(&bins[f], src[i]);
    }
    __syncthreads();
    if (t < F_) partial[b * F_ + t] = bins[t];
  } else {
    __shared__ float red[4];
    int k = b - CS_BLOCKS;
    float acc = 0.f;
    if (t < H2_ / 4) {
      const float4 w = reinterpret_cast<const float4*>(W2 + (size_t)k * H2_)[t];
      const float4 gg = reinterpret_cast<const float4*>(g2)[t];
      acc = w.x * gg.x + w.y * gg.y + w.z * gg.z + w.w * gg.w;
    }
    float tot = blockReduceSum256(acc, red);
    if (t == 0) {
      w2red[k] = tot;
      w2g[k] = tot * g1[k];
    }
  }
}

// ---- pre2:
//   blocks 0..623 : A[m] = c^2 * W1[m,:]·w2g   (float4)
//   block 624     : consts[0] = C_mlp
//   blocks 625..663: colsum[f] = sum_b partial[b][f]
__global__ __launch_bounds__(256) void pre2_kernel(
    const float* __restrict__ W1, const float* __restrict__ b1,
    const float* __restrict__ g1, const float* __restrict__ beta1,
    const float* __restrict__ b2, const float* __restrict__ g2,
    const float* __restrict__ beta2, const float* __restrict__ w2red,
    const float* __restrict__ w2g, const float* __restrict__ partial,
    float* __restrict__ A, float* __restrict__ colsum,
    float* __restrict__ consts) {
  __shared__ float red[4];
  const float c = 1.0f / sqrtf(1.0f + 1e-5f);
  int b = blockIdx.x, t = threadIdx.x;
  if (b < FE_) {
    float acc = 0.f;
    if (t < H1_ / 4) {
      const float4 w = reinterpret_cast<const float4*>(W1 + (size_t)b * H1_)[t];
      const float4 gg = reinterpret_cast<const float4*>(w2g)[t];
      acc = w.x * gg.x + w.y * gg.y + w.z * gg.z + w.w * gg.w;
    }
    float tot = blockReduceSum256(acc, red);
    if (t == 0) A[b] = c * c * tot;
  } else if (b == FE_) {
    // C_mlp = c^2*(b1*g1)·w2red + c*beta1·w2red + c*(g2·b2) + sum(beta2)
    float acc = 0.f;
    for (int k = t; k < H1_; k += 256) {
      float wr = w2red[k];
      acc += c * c * b1[k] * g1[k] * wr + c * beta1[k] * wr;
    }
    for (int j = t; j < H2_; j += 256) acc += c * g2[j] * b2[j] + beta2[j];
    float tot = blockReduceSum256(acc, red);
    if (t == 0) consts[0] = tot;
  } else {
    int f = b - FE_ - 1;  // 0..38
    float acc = (t < CS_BLOCKS) ? partial[t * F_ + f] : 0.f;
    float tot = blockReduceSum256(acc, red);
    if (t == 0) colsum[f] = tot;
  }
}

// ---- main: 32 lanes per sample (8 feature-slots x 4 element-quads),
//            8 samples per 256-thread block, float4 gathers.
__global__ __launch_bounds__(256, 8) void fused_main(
    const int* __restrict__ Xi, const float* __restrict__ Xv,
    const float* __restrict__ emb1, const float* __restrict__ emb2,
    const float* __restrict__ colsum, const float* __restrict__ A,
    const float* __restrict__ consts, const float* __restrict__ bias,
    float* __restrict__ out) {
  __shared__ int s_ix[SPB][F_ + 1];
  __shared__ float s_xv[SPB][F_ + 1];
  __shared__ __align__(16) float s_A[FE_];
  __shared__ float s_cs[F_];
  int t = threadIdx.x;
  int n0 = blockIdx.x * SPB;

  for (int i = t; i < FE_; i += 256) s_A[i] = A[i];
  if (t < F_) s_cs[t] = colsum[t];
  for (int i = t; i < SPB * F_; i += 256) {
    int smp = i / F_, f = i - smp * F_;
    s_ix[smp][f] = Xi[(n0 + smp) * F_ + f];
    s_xv[smp][f] = Xv[(n0 + smp) * F_ + f];
  }
  __syncthreads();

  int g = t >> 5;   // sample within block, 0..7
  int l = t & 31;   // lane within sample group
  int q = l & 3;    // element quad: elems 4q..4q+3
  int fs = l >> 2;  // feature slot 0..7; features fs, fs+8, fs+16, fs+24, fs+32

  float4 s4 = make_float4(0.f, 0.f, 0.f, 0.f);
  float sq = 0.f, lin = 0.f, first = 0.f;

#pragma unroll
  for (int i = 0; i < 5; ++i) {
    int f = fs + 8 * i;
    if (f < F_) {
      int ix = s_ix[g][f];
      float v = s_xv[g][f];
      // 4 lanes x float4 cover one 64B emb2 row segment
      const float4 e = *reinterpret_cast<const float4*>(
          emb2 + ((size_t)(f * V_ + ix)) * E_ + 4 * q);
      float xx = e.x * v, xy = e.y * v, xz = e.z * v, xw = e.w * v;
      s4.x += xx; s4.y += xy; s4.z += xz; s4.w += xw;
      sq += xx * xx + xy * xy + xz * xz + xw * xw;
      const float4 a = *reinterpret_cast<const float4*>(&s_A[f * E_ + 4 * q]);
      lin += xx * a.x + xy * a.y + xz * a.z + xw * a.w;
    }
  }

  // first-order: lane l covers features l and l+32
  for (int f = l; f < F_; f += 32) {
    first += emb1[(size_t)f * V_ + s_ix[g][f]] * s_cs[f];
  }

  // complete per-element sums: combine the 8 feature-slots
  s4.x += __shfl_xor(s4.x, 4);  s4.y += __shfl_xor(s4.y, 4);
  s4.z += __shfl_xor(s4.z, 4);  s4.w += __shfl_xor(s4.w, 4);
  s4.x += __shfl_xor(s4.x, 8);  s4.y += __shfl_xor(s4.y, 8);
  s4.z += __shfl_xor(s4.z, 8);  s4.w += __shfl_xor(s4.w, 8);
  s4.x += __shfl_xor(s4.x, 16); s4.y += __shfl_xor(s4.y, 16);
  s4.z += __shfl_xor(s4.z, 16); s4.w += __shfl_xor(s4.w, 16);

  float ss = s4.x * s4.x + s4.y * s4.y + s4.z * s4.z + s4.w * s4.w;
  // s^2 term contributed once per element-quad (lanes fs==0, i.e. l=0..3)
  float tv = (fs == 0 ? 0.5f * ss : 0.f) - 0.5f * sq + lin + first;

  tv += __shfl_xor(tv, 1);
  tv += __shfl_xor(tv, 2);
  tv += __shfl_xor(tv, 4);
  tv += __shfl_xor(tv, 8);
  tv += __shfl_xor(tv, 16);

  if (l == 0) out[n0 + g] = tv + consts[0] + bias[0];
}

extern "C" void kernel_launch(void* const* d_in, const int* in_sizes, int n_in,
                              void* d_out, int out_size, void* d_ws,
                              size_t ws_size, hipStream_t stream) {
  const int* Xi = (const int*)d_in[0];
  const float* Xv = (const float*)d_in[1];
  const float* emb1 = (const float*)d_in[2];
  const float* emb2 = (const float*)d_in[3];
  const float* W1 = (const float*)d_in[4];
  const float* b1 = (const float*)d_in[5];
  const float* W2 = (const float*)d_in[6];
  const float* b2 = (const float*)d_in[7];
  const float* g1 = (const float*)d_in[8];
  const float* beta1 = (const float*)d_in[9];
  const float* g2 = (const float*)d_in[10];
  const float* beta2 = (const float*)d_in[11];
  const float* bias = (const float*)d_in[12];
  float* out = (float*)d_out;

  float* ws = (float*)d_ws;
  float* colsum = ws;           // 39   (slots 0..63)
  float* w2red = ws + 64;       // 400  (64..511)
  float* w2g = ws + 512;        // 400  (512..959), 16B-aligned
  float* A = ws + 960;          // 624  (960..1599)
  float* consts = ws + 1600;    // 1
  float* partial = ws + 2048;   // 256*39 = 9984 floats

  pre1_kernel<<<CS_BLOCKS + H1_, 256, 0, stream>>>(Xv, W2, g1, g2, partial,
                                                   w2red, w2g);
  pre2_kernel<<<FE_ + 1 + F_, 256, 0, stream>>>(W1, b1, g1, beta1, b2, g2,
                                                beta2, w2red, w2g, partial, A,
                                                colsum, consts);
  fused_main<<<N_SAMPLES / SPB, 256, 0, stream>>>(Xi, Xv, emb1, emb2, colsum,
                                                  A, consts, bias, out);
}

// Round 2
// 332.407 us; speedup vs baseline: 1.1189x; 1.0386x over previous
//
#include <hip/hip_runtime.h>
#include <cstddef>

#define N_SAMPLES 16384
#define F_ 39
#define V_ 100000
#define E_ 16
#define H1_ 400
#define H2_ 400
#define FE_ (F_ * E_)  // 624

#define CS_BLOCKS 256
#define CS_CHUNK (N_SAMPLES / CS_BLOCKS)  // 64 rows per block
#define SPB 8                              // samples per block in fused_main

// ---- block-wide sum over 256 threads; result valid on threadIdx.x==0 ----
__device__ __forceinline__ float blockReduceSum256(float v, float* red) {
  int t = threadIdx.x;
  v += __shfl_xor(v, 32);
  v += __shfl_xor(v, 16);
  v += __shfl_xor(v, 8);
  v += __shfl_xor(v, 4);
  v += __shfl_xor(v, 2);
  v += __shfl_xor(v, 1);
  if ((t & 63) == 0) red[t >> 6] = v;
  __syncthreads();
  if (t == 0) v = red[0] + red[1] + red[2] + red[3];
  return v;
}

// ---- pre1:
//   blocks 0..255   : coalesced partial column-sums of Xv -> partial[b][f]
//   blocks 256..655 : w2red[k] = W2[k,:]·g2  (float4), w2g[k] = g1[k]*w2red[k]
__global__ __launch_bounds__(256) void pre1_kernel(
    const float* __restrict__ Xv, const float* __restrict__ W2,
    const float* __restrict__ g1, const float* __restrict__ g2,
    float* __restrict__ partial, float* __restrict__ w2red,
    float* __restrict__ w2g) {
  int b = blockIdx.x, t = threadIdx.x;
  if (b < CS_BLOCKS) {
    __shared__ float bins[F_];
    if (t < F_) bins[t] = 0.f;
    __syncthreads();
    const float* src = Xv + (size_t)b * CS_CHUNK * F_;
    for (int i = t; i < CS_CHUNK * F_; i += 256) {
      int f = i % F_;
      atomicAdd(&bins[f], src[i]);
    }
    __syncthreads();
    if (t < F_) partial[b * F_ + t] = bins[t];
  } else {
    __shared__ float red[4];
    int k = b - CS_BLOCKS;
    float acc = 0.f;
    if (t < H2_ / 4) {
      const float4 w = reinterpret_cast<const float4*>(W2 + (size_t)k * H2_)[t];
      const float4 gg = reinterpret_cast<const float4*>(g2)[t];
      acc = w.x * gg.x + w.y * gg.y + w.z * gg.z + w.w * gg.w;
    }
    float tot = blockReduceSum256(acc, red);
    if (t == 0) {
      w2red[k] = tot;
      w2g[k] = tot * g1[k];
    }
  }
}

// ---- pre2:
//   blocks 0..623 : A[m] = c^2 * W1[m,:]·w2g   (float4)
//   block 624     : consts[0] = C_mlp
//   blocks 625..663: colsum[f] = sum_b partial[b][f]
__global__ __launch_bounds__(256) void pre2_kernel(
    const float* __restrict__ W1, const float* __restrict__ b1,
    const float* __restrict__ g1, const float* __restrict__ beta1,
    const float* __restrict__ b2, const float* __restrict__ g2,
    const float* __restrict__ beta2, const float* __restrict__ w2red,
    const float* __restrict__ w2g, const float* __restrict__ partial,
    float* __restrict__ A, float* __restrict__ colsum,
    float* __restrict__ consts) {
  __shared__ float red[4];
  const float c = 1.0f / sqrtf(1.0f + 1e-5f);
  int b = blockIdx.x, t = threadIdx.x;
  if (b < FE_) {
    float acc = 0.f;
    if (t < H1_ / 4) {
      const float4 w = reinterpret_cast<const float4*>(W1 + (size_t)b * H1_)[t];
      const float4 gg = reinterpret_cast<const float4*>(w2g)[t];
      acc = w.x * gg.x + w.y * gg.y + w.z * gg.z + w.w * gg.w;
    }
    float tot = blockReduceSum256(acc, red);
    if (t == 0) A[b] = c * c * tot;
  } else if (b == FE_) {
    float acc = 0.f;
    for (int k = t; k < H1_; k += 256) {
      float wr = w2red[k];
      acc += c * c * b1[k] * g1[k] * wr + c * beta1[k] * wr;
    }
    for (int j = t; j < H2_; j += 256) acc += c * g2[j] * b2[j] + beta2[j];
    float tot = blockReduceSum256(acc, red);
    if (t == 0) consts[0] = tot;
  } else {
    int f = b - FE_ - 1;  // 0..38
    float acc = (t < CS_BLOCKS) ? partial[t * F_ + f] : 0.f;
    float tot = blockReduceSum256(acc, red);
    if (t == 0) colsum[f] = tot;
  }
}

// ---- main: 32 lanes per sample (8 feature-slots x 4 element-quads),
//            8 samples per 256-thread block.
//   Two-phase body: issue ALL gathers unconditionally (clamped addresses,
//   zeroed multipliers for invalid slots) so 5 float4 + 2 scalar loads are
//   simultaneously in flight, then a pure-FMA phase.
__global__ __launch_bounds__(256, 8) void fused_main(
    const int* __restrict__ Xi, const float* __restrict__ Xv,
    const float* __restrict__ emb1, const float* __restrict__ emb2,
    const float* __restrict__ colsum, const float* __restrict__ A,
    const float* __restrict__ consts, const float* __restrict__ bias,
    float* __restrict__ out) {
  __shared__ int s_ix[SPB][F_ + 1];
  __shared__ float s_xv[SPB][F_ + 1];
  __shared__ __align__(16) float s_A[FE_];
  __shared__ float s_cs[F_];
  int t = threadIdx.x;
  int n0 = blockIdx.x * SPB;

  for (int i = t; i < FE_; i += 256) s_A[i] = A[i];
  if (t < F_) s_cs[t] = colsum[t];
  for (int i = t; i < SPB * F_; i += 256) {
    int smp = i / F_, f = i - smp * F_;
    s_ix[smp][f] = Xi[(n0 + smp) * F_ + f];
    s_xv[smp][f] = Xv[(n0 + smp) * F_ + f];
  }
  __syncthreads();

  int g = t >> 5;   // sample within block, 0..7
  int l = t & 31;   // lane within sample group
  int q = l & 3;    // element quad: elems 4q..4q+3
  int fs = l >> 2;  // feature slot 0..7; features fs, fs+8, ..., fs+32

  // ---- phase 1: issue everything ----
  float4 e0, e1v, e2v, e3v, e4v;
  float v0, v1, v2, v3, v4;
  int fc0, fc1, fc2, fc3, fc4;
  {
    int f;
    f = fs;            fc0 = f;                v0 = s_xv[g][fc0];
    f = fs + 8;        fc1 = f;                v1 = s_xv[g][fc1];
    f = fs + 16;       fc2 = f;                v2 = s_xv[g][fc2];
    f = fs + 24;       fc3 = f;                v3 = s_xv[g][fc3];
    f = fs + 32;       fc4 = (f < F_) ? f : 0; v4 = (f < F_) ? s_xv[g][fc4] : 0.f;
  }
  e0 = *reinterpret_cast<const float4*>(emb2 + ((size_t)(fc0 * V_ + s_ix[g][fc0])) * E_ + 4 * q);
  e1v = *reinterpret_cast<const float4*>(emb2 + ((size_t)(fc1 * V_ + s_ix[g][fc1])) * E_ + 4 * q);
  e2v = *reinterpret_cast<const float4*>(emb2 + ((size_t)(fc2 * V_ + s_ix[g][fc2])) * E_ + 4 * q);
  e3v = *reinterpret_cast<const float4*>(emb2 + ((size_t)(fc3 * V_ + s_ix[g][fc3])) * E_ + 4 * q);
  e4v = *reinterpret_cast<const float4*>(emb2 + ((size_t)(fc4 * V_ + s_ix[g][fc4])) * E_ + 4 * q);

  // first-order gathers: lane l covers features l and (l+32 if valid)
  int f1a = l;                               // l <= 31 < 39, always valid
  int f1b_raw = l + 32;
  int f1b = (f1b_raw < F_) ? f1b_raw : 0;
  float m1b = (f1b_raw < F_) ? 1.f : 0.f;
  float ea = emb1[(size_t)f1a * V_ + s_ix[g][f1a]];
  float eb = emb1[(size_t)f1b * V_ + s_ix[g][f1b]];

  // ---- phase 2: pure compute ----
  float4 s4 = make_float4(0.f, 0.f, 0.f, 0.f);
  float sq = 0.f, lin = 0.f;

#define ACCUM(EV, VV, FC)                                                   \
  {                                                                         \
    float xx = (EV).x * (VV), xy = (EV).y * (VV), xz = (EV).z * (VV),       \
          xw = (EV).w * (VV);                                               \
    s4.x += xx; s4.y += xy; s4.z += xz; s4.w += xw;                         \
    sq += xx * xx + xy * xy + xz * xz + xw * xw;                            \
    const float4 a = *reinterpret_cast<const float4*>(&s_A[(FC)*E_ + 4*q]); \
    lin += xx * a.x + xy * a.y + xz * a.z + xw * a.w;                       \
  }
  ACCUM(e0, v0, fc0)
  ACCUM(e1v, v1, fc1)
  ACCUM(e2v, v2, fc2)
  ACCUM(e3v, v3, fc3)
  ACCUM(e4v, v4, fc4)
#undef ACCUM

  float first = ea * s_cs[f1a] + m1b * eb * s_cs[f1b];

  // complete per-element sums: combine the 8 feature-slots
  s4.x += __shfl_xor(s4.x, 4);  s4.y += __shfl_xor(s4.y, 4);
  s4.z += __shfl_xor(s4.z, 4);  s4.w += __shfl_xor(s4.w, 4);
  s4.x += __shfl_xor(s4.x, 8);  s4.y += __shfl_xor(s4.y, 8);
  s4.z += __shfl_xor(s4.z, 8);  s4.w += __shfl_xor(s4.w, 8);
  s4.x += __shfl_xor(s4.x, 16); s4.y += __shfl_xor(s4.y, 16);
  s4.z += __shfl_xor(s4.z, 16); s4.w += __shfl_xor(s4.w, 16);

  float ss = s4.x * s4.x + s4.y * s4.y + s4.z * s4.z + s4.w * s4.w;
  float tv = (fs == 0 ? 0.5f * ss : 0.f) - 0.5f * sq + lin + first;

  tv += __shfl_xor(tv, 1);
  tv += __shfl_xor(tv, 2);
  tv += __shfl_xor(tv, 4);
  tv += __shfl_xor(tv, 8);
  tv += __shfl_xor(tv, 16);

  if (l == 0) out[n0 + g] = tv + consts[0] + bias[0];
}

extern "C" void kernel_launch(void* const* d_in, const int* in_sizes, int n_in,
                              void* d_out, int out_size, void* d_ws,
                              size_t ws_size, hipStream_t stream) {
  const int* Xi = (const int*)d_in[0];
  const float* Xv = (const float*)d_in[1];
  const float* emb1 = (const float*)d_in[2];
  const float* emb2 = (const float*)d_in[3];
  const float* W1 = (const float*)d_in[4];
  const float* b1 = (const float*)d_in[5];
  const float* W2 = (const float*)d_in[6];
  const float* b2 = (const float*)d_in[7];
  const float* g1 = (const float*)d_in[8];
  const float* beta1 = (const float*)d_in[9];
  const float* g2 = (const float*)d_in[10];
  const float* beta2 = (const float*)d_in[11];
  const float* bias = (const float*)d_in[12];
  float* out = (float*)d_out;

  float* ws = (float*)d_ws;
  float* colsum = ws;           // 39   (slots 0..63)
  float* w2red = ws + 64;       // 400  (64..511)
  float* w2g = ws + 512;        // 400  (512..959), 16B-aligned
  float* A = ws + 960;          // 624  (960..1599)
  float* consts = ws + 1600;    // 1
  float* partial = ws + 2048;   // 256*39 = 9984 floats

  pre1_kernel<<<CS_BLOCKS + H1_, 256, 0, stream>>>(Xv, W2, g1, g2, partial,
                                                   w2red, w2g);
  pre2_kernel<<<FE_ + 1 + F_, 256, 0, stream>>>(W1, b1, g1, beta1, b2, g2,
                                                beta2, w2red, w2g, partial, A,
                                                colsum, consts);
  fused_main<<<N_SAMPLES / SPB, 256, 0, stream>>>(Xi, Xv, emb1, emb2, colsum,
                                                  A, consts, bias, out);
}